// Round 16
// baseline (249.168 us; speedup 1.0000x reference)
//
#include <hip/hip_runtime.h>
#include <math.h>

#define Dd 96
#define Nn 48
#define LD 97

// One block per particle k. P is FLOAT32 (f64 reference inputs downcast to f32
// by the harness — NOT bf16; reading it as bf16 was the round-2..15 poison).
// A_k = (I - P P^T) - diag(occ<k) staged in LDS (f64 accumulation); since P is
// f32-accurate, G is a near-exact projector: unpivoted-LU pivots are the DPP's
// conditional-empty probabilities in (0, ~1+1e-6].
// probs[k,x] = S(x)*(1 - pivot_x), S(x) = prod_{l=xmin}^{x-1} pivot_l
// (telescoping of the reference's -(d_{x+1}-d_x)/d_xmin — the stable form).
// Guards only trim the structural tail / trap junk:
//   in-window: pivot floor 1e-7, band < 8, S-floor 1e-8 (post-cut true mass
//   <= 1e-7 << tol 1.77e-2); pre-window: floor 1e-12 (legit conditionals are
//   O(0.01..1)); emit-before-cut keeps the cut site's real mass.
__global__ __launch_bounds__(256) void slater_kernel(const float* __restrict__ P,
                                                     const int* __restrict__ occ,
                                                     float* __restrict__ out) {
    __shared__ double As[Dd * LD];      // 74,496 B
    __shared__ unsigned char flag[Dd];

    const int tid  = threadIdx.x;
    const int k    = blockIdx.x;
    const int n    = Dd - Nn + k + 1;   // xmax
    const int lane = tid & 63;
    const int wave = tid >> 6;
    const int xmin = (k == 0) ? 0 : occ[k - 1] + 1;

    if (tid < Dd) flag[tid] = 0;
    __syncthreads();
    if (tid < k) flag[occ[tid]] = 1;    // particles 0..k-1
    __syncthreads();

    // Stage A_k (leading n x n): A_rc = delta_rc*(1-flag_r) - P_r . P_c
    for (int e = tid; e < n * n; e += 256) {
        int r = e / n, c = e - (e / n) * n;
        double s = (r == c) ? (flag[r] ? 0.0 : 1.0) : 0.0;
        const float* Pr = P + r * Nn;
        const float* Pc = P + c * Nn;
#pragma unroll
        for (int t = 0; t < Nn; ++t)
            s -= (double)Pr[t] * (double)Pc[t];
        As[r * LD + c] = s;
    }
    __syncthreads();

    // Survival-product unpivoted LU; pivot/runprod/dead are uniform across the
    // block (same-address LDS read + identical scalar arithmetic).
    double runprod = 1.0;   // S: prod of pivots from l = xmin
    double myprob  = 0.0;   // this thread's probs[k, tid]
    bool   dead    = false;

    for (int j = 0; j < n - 1; ++j) {
        double pivot = As[j * LD + j];
        double ap = fabs(pivot);
        if (j >= xmin) {
            if (tid == j) myprob = runprod * (1.0 - pivot);  // emit BEFORE any cut
            double newrun = runprod * pivot;
            if (!(ap > 1e-7) || !(ap < 8.0) || !(fabs(newrun) > 1e-8)) { dead = true; break; }
            runprod = newrun;
        } else {
            if (!(ap > 1e-12) || !(ap < 8.0)) { dead = true; break; }
        }
        double rp = 1.0 / pivot;
        int t = n - 1 - j;                       // trailing width
        double r0 = (lane < t)      ? As[j * LD + j + 1 + lane]  : 0.0;
        double r1 = (lane + 64 < t) ? As[j * LD + j + 65 + lane] : 0.0;
        for (int i = j + 1 + wave; i < n; i += 4) {
            double mult = As[i * LD + j] * rp;   // broadcast read
            if (lane < t)      As[i * LD + j + 1 + lane]  -= mult * r0;
            if (lane + 64 < t) As[i * LD + j + 65 + lane] -= mult * r1;
        }
        __syncthreads();
    }
    if (!dead && tid == n - 1) {                 // last support site x = xmax-1:
        double pl = As[(n - 1) * LD + (n - 1)];  // structural-zero ratio (~1e-7)
        myprob = runprod * (1.0 - pl);           // = remaining mass (stable form)
    }

    if (tid < Dd) {
        double p = myprob;                       // 0 outside emitted support
        if (!isfinite(p)) p = 0.0;
        if (!(fabs(p) > 1e-15)) p = 0.0;         // reference's flush
        p = fmin(fmax(p, 0.0), 1.0);             // ref range [0, 0.887]; junk-proof
        out[k * Dd + tid] = (float)p;
    }
}

// prob_sample = prod_k probs[k, occ[k]] (f64 product; true value ~1e-40 -> ~0
// in f32 on both sides).
__global__ void prod_kernel(const int* __restrict__ occ, float* __restrict__ out) {
    if (threadIdx.x == 0) {
        double v = 1.0;
        for (int k = 0; k < Nn; ++k) v *= (double)out[k * Dd + occ[k]];
        if (!isfinite(v)) v = 0.0;
        out[Nn * Dd] = (float)v;
    }
}

extern "C" void kernel_launch(void* const* d_in, const int* in_sizes, int n_in,
                              void* d_out, int out_size, void* d_ws, size_t ws_size,
                              hipStream_t stream) {
    const float* P = (const float*)d_in[0];      // 96x48 f32, row-major
    const int* occ = (const int*)d_in[1];        // 48 int32
    float* out = (float*)d_out;                  // 4609 f32

    slater_kernel<<<Nn, 256, 0, stream>>>(P, occ, out);
    prod_kernel<<<1, 64, 0, stream>>>(occ, out);
}

// Round 17
// 233.459 us; speedup vs baseline: 1.0673x; 1.0673x over previous
//
#include <hip/hip_runtime.h>
#include <math.h>

#define Dd 96
#define Nn 48
#define LD 97
#define PTS 97   // PT row stride in floats (PT[t][c], c stride-1 across lanes)

// One block per particle k (P is f32 — verified R16, absmax 7.4e-9).
// R17 change: kill the 185-us global-gather in staging. P is staged once into
// LDS transposed (PT[t][c], conflict-free lane access), A = I*(1-flag) - P P^T
// is built in registers from 2x2 tiles (halves LDS instruction count), then the
// R16-proven survival-product LU runs unchanged.
__global__ __launch_bounds__(256) void slater_kernel(const float* __restrict__ P,
                                                     const int* __restrict__ occ,
                                                     float* __restrict__ out) {
    __shared__ double As[Dd * LD];      // 74,496 B (proven footprint)
    __shared__ unsigned char flag[Dd];
    float* PT = (float*)As;             // scratch alias; all PT reads precede As writes

    const int tid  = threadIdx.x;
    const int k    = blockIdx.x;
    const int n    = Dd - Nn + k + 1;   // xmax
    const int lane = tid & 63;
    const int wave = tid >> 6;
    const int xmin = (k == 0) ? 0 : occ[k - 1] + 1;

    if (tid < Dd) flag[tid] = 0;
    __syncthreads();
    if (tid < k) flag[occ[tid]] = 1;    // particles 0..k-1
    // Stage P transposed: PT[t][c] = P[c][t]  (global reads coalesced over e)
    for (int e = tid; e < Dd * Nn; e += 256) {
        int c = e / Nn, t = e - (e / Nn) * Nn;
        PT[t * PTS + c] = P[e];
    }
    __syncthreads();

    // Build A into registers: 2x2 tiles, fixed 48 tiles per tile-row
    // (covers r,c < 96; 2304 tiles = 9 per thread). Reads: 2 broadcast (r) +
    // 2 stride-2 (c) per t — ~1728 LDS instr/wave vs 3456 untiled.
    double Areg[36];
#pragma unroll
    for (int it = 0; it < 9; ++it) {
        int tau = tid + 256 * it;
        int tr = tau / 48, tc = tau - (tau / 48) * 48;
        int r0 = 2 * tr, c0 = 2 * tc;
        double s00 = 0.0, s01 = 0.0, s10 = 0.0, s11 = 0.0;
        if (r0 < n && c0 < n) {
            for (int t = 0; t < Nn; ++t) {
                const float* row = PT + t * PTS;
                double pr0 = (double)row[r0];
                double pr1 = (double)row[r0 + 1];   // r0+1 <= 95: always valid data
                double pc0 = (double)row[c0];
                double pc1 = (double)row[c0 + 1];
                s00 -= pr0 * pc0; s01 -= pr0 * pc1;
                s10 -= pr1 * pc0; s11 -= pr1 * pc1;
            }
        }
        Areg[it * 4 + 0] = s00; Areg[it * 4 + 1] = s01;
        Areg[it * 4 + 2] = s10; Areg[it * 4 + 3] = s11;
    }
    __syncthreads();                    // all PT reads done before As overwrite
#pragma unroll
    for (int it = 0; it < 9; ++it) {
        int tau = tid + 256 * it;
        int tr = tau / 48, tc = tau - (tau / 48) * 48;
        int r0 = 2 * tr, c0 = 2 * tc;
        if (r0 < n && c0 < n) {
            bool r1ok = (r0 + 1 < n), c1ok = (c0 + 1 < n);
            double d00 = (r0 == c0) ? (flag[r0] ? 0.0 : 1.0) : 0.0;
            As[r0 * LD + c0] = Areg[it * 4 + 0] + d00;
            if (c1ok) {
                double d01 = (r0 == c0 + 1) ? (flag[r0] ? 0.0 : 1.0) : 0.0;
                As[r0 * LD + c0 + 1] = Areg[it * 4 + 1] + d01;
            }
            if (r1ok) {
                double d10 = (r0 + 1 == c0) ? (flag[r0 + 1] ? 0.0 : 1.0) : 0.0;
                As[(r0 + 1) * LD + c0] = Areg[it * 4 + 2] + d10;
            }
            if (r1ok && c1ok) {
                double d11 = (r0 + 1 == c0 + 1) ? (flag[r0 + 1] ? 0.0 : 1.0) : 0.0;
                As[(r0 + 1) * LD + c0 + 1] = Areg[it * 4 + 3] + d11;
            }
        }
    }
    __syncthreads();

    // ---- Survival-product unpivoted LU (R16-proven, unchanged) ----
    double runprod = 1.0;
    double myprob  = 0.0;
    bool   dead    = false;

    for (int j = 0; j < n - 1; ++j) {
        double pivot = As[j * LD + j];
        double ap = fabs(pivot);
        if (j >= xmin) {
            if (tid == j) myprob = runprod * (1.0 - pivot);  // emit BEFORE any cut
            double newrun = runprod * pivot;
            if (!(ap > 1e-7) || !(ap < 8.0) || !(fabs(newrun) > 1e-8)) { dead = true; break; }
            runprod = newrun;
        } else {
            if (!(ap > 1e-12) || !(ap < 8.0)) { dead = true; break; }
        }
        double rp = 1.0 / pivot;
        int t = n - 1 - j;
        double r0 = (lane < t)      ? As[j * LD + j + 1 + lane]  : 0.0;
        double r1 = (lane + 64 < t) ? As[j * LD + j + 65 + lane] : 0.0;
        for (int i = j + 1 + wave; i < n; i += 4) {
            double mult = As[i * LD + j] * rp;   // broadcast read
            if (lane < t)      As[i * LD + j + 1 + lane]  -= mult * r0;
            if (lane + 64 < t) As[i * LD + j + 65 + lane] -= mult * r1;
        }
        __syncthreads();
    }
    if (!dead && tid == n - 1) {
        double pl = As[(n - 1) * LD + (n - 1)];
        myprob = runprod * (1.0 - pl);
    }

    if (tid < Dd) {
        double p = myprob;
        if (!isfinite(p)) p = 0.0;
        if (!(fabs(p) > 1e-15)) p = 0.0;   // reference's flush
        p = fmin(fmax(p, 0.0), 1.0);       // junk-proof projection
        out[k * Dd + tid] = (float)p;
    }
}

// prob_sample = prod_k probs[k, occ[k]]
__global__ void prod_kernel(const int* __restrict__ occ, float* __restrict__ out) {
    if (threadIdx.x == 0) {
        double v = 1.0;
        for (int k = 0; k < Nn; ++k) v *= (double)out[k * Dd + occ[k]];
        if (!isfinite(v)) v = 0.0;
        out[Nn * Dd] = (float)v;
    }
}

extern "C" void kernel_launch(void* const* d_in, const int* in_sizes, int n_in,
                              void* d_out, int out_size, void* d_ws, size_t ws_size,
                              hipStream_t stream) {
    const float* P = (const float*)d_in[0];      // 96x48 f32, row-major
    const int* occ = (const int*)d_in[1];        // 48 int32
    float* out = (float*)d_out;                  // 4609 f32

    slater_kernel<<<Nn, 256, 0, stream>>>(P, occ, out);
    prod_kernel<<<1, 64, 0, stream>>>(occ, out);
}

// Round 18
// 231.999 us; speedup vs baseline: 1.0740x; 1.0063x over previous
//
#include <hip/hip_runtime.h>
#include <math.h>

#define Dd 96
#define Nn 48
#define LD 97
#define PTS 97   // PT row stride in floats

// One block per particle k (P is f32 — R16-verified, absmax 7.4e-9).
// R18 change: the LU row-update loop was latency-serialized (~250 LDS-latency
// cycles per row, ~118 us total). Batch 8 rows per wave: all 8 multiplier
// reads issued independently, then 16 row-element reads, then writes —
// latency paid per batch, ~6x less stall. Guards/arithmetic identical to R16.
__global__ __launch_bounds__(256) void slater_kernel(const float* __restrict__ P,
                                                     const int* __restrict__ occ,
                                                     float* __restrict__ out) {
    __shared__ double As[Dd * LD];      // 74,496 B
    __shared__ unsigned char flag[Dd];
    float* PT = (float*)As;             // scratch alias; PT reads end before As writes

    const int tid  = threadIdx.x;
    const int k    = blockIdx.x;
    const int n    = Dd - Nn + k + 1;   // xmax
    const int lane = tid & 63;
    const int wave = tid >> 6;
    const int xmin = (k == 0) ? 0 : occ[k - 1] + 1;

    if (tid < Dd) flag[tid] = 0;
    __syncthreads();
    if (tid < k) flag[occ[tid]] = 1;
    // Stage P transposed into LDS: PT[t][c] = P[c][t]
    for (int e = tid; e < Dd * Nn; e += 256) {
        int c = e / Nn, t = e - (e / Nn) * Nn;
        PT[t * PTS + c] = P[e];
    }
    __syncthreads();

    // Build A = I*(1-flag) - P P^T in registers via 2x2 tiles (R17 staging).
    double Areg[36];
#pragma unroll
    for (int it = 0; it < 9; ++it) {
        int tau = tid + 256 * it;
        int tr = tau / 48, tc = tau - (tau / 48) * 48;
        int r0 = 2 * tr, c0 = 2 * tc;
        double s00 = 0.0, s01 = 0.0, s10 = 0.0, s11 = 0.0;
        if (r0 < n && c0 < n) {
            for (int t = 0; t < Nn; ++t) {
                const float* row = PT + t * PTS;
                double pr0 = (double)row[r0];
                double pr1 = (double)row[r0 + 1];
                double pc0 = (double)row[c0];
                double pc1 = (double)row[c0 + 1];
                s00 -= pr0 * pc0; s01 -= pr0 * pc1;
                s10 -= pr1 * pc0; s11 -= pr1 * pc1;
            }
        }
        Areg[it * 4 + 0] = s00; Areg[it * 4 + 1] = s01;
        Areg[it * 4 + 2] = s10; Areg[it * 4 + 3] = s11;
    }
    __syncthreads();
#pragma unroll
    for (int it = 0; it < 9; ++it) {
        int tau = tid + 256 * it;
        int tr = tau / 48, tc = tau - (tau / 48) * 48;
        int r0 = 2 * tr, c0 = 2 * tc;
        if (r0 < n && c0 < n) {
            bool r1ok = (r0 + 1 < n), c1ok = (c0 + 1 < n);
            double d00 = (r0 == c0) ? (flag[r0] ? 0.0 : 1.0) : 0.0;
            As[r0 * LD + c0] = Areg[it * 4 + 0] + d00;
            if (c1ok) {
                double d01 = (r0 == c0 + 1) ? (flag[r0] ? 0.0 : 1.0) : 0.0;
                As[r0 * LD + c0 + 1] = Areg[it * 4 + 1] + d01;
            }
            if (r1ok) {
                double d10 = (r0 + 1 == c0) ? (flag[r0 + 1] ? 0.0 : 1.0) : 0.0;
                As[(r0 + 1) * LD + c0] = Areg[it * 4 + 2] + d10;
            }
            if (r1ok && c1ok) {
                double d11 = (r0 + 1 == c0 + 1) ? (flag[r0 + 1] ? 0.0 : 1.0) : 0.0;
                As[(r0 + 1) * LD + c0 + 1] = Areg[it * 4 + 3] + d11;
            }
        }
    }
    __syncthreads();

    // ---- Survival-product unpivoted LU, 8-row-batched updates ----
    double runprod = 1.0;
    double myprob  = 0.0;
    bool   dead    = false;

    for (int j = 0; j < n - 1; ++j) {
        double pivot = As[j * LD + j];       // same-address broadcast, uniform
        double ap = fabs(pivot);
        if (j >= xmin) {
            if (tid == j) myprob = runprod * (1.0 - pivot);  // emit BEFORE any cut
            double newrun = runprod * pivot;
            if (!(ap > 1e-7) || !(ap < 8.0) || !(fabs(newrun) > 1e-8)) { dead = true; break; }
            runprod = newrun;
        } else {
            if (!(ap > 1e-12) || !(ap < 8.0)) { dead = true; break; }
        }
        double rp = 1.0 / pivot;
        int t = n - 1 - j;                   // trailing width
        double r0 = (lane < t)      ? As[j * LD + j + 1 + lane]  : 0.0;
        double r1 = (lane + 64 < t) ? As[j * LD + j + 65 + lane] : 0.0;

        // Rows i = j+1+wave, step 4 (wave-disjoint). Batch 8 rows: independent
        // reads issued together -> LDS latency overlapped within the batch.
        for (int i0 = j + 1 + wave; i0 < n; i0 += 32) {
            int    iu[8];
            double mult[8], c0v[8], c1v[8];
#pragma unroll
            for (int u = 0; u < 8; ++u) {
                int i = i0 + 4 * u;
                iu[u] = (i < n) ? i : (n - 1);       // clamped: safe, discarded
                mult[u] = As[iu[u] * LD + j] * rp;   // col j: read-only this step
            }
#pragma unroll
            for (int u = 0; u < 8; ++u) {
                c0v[u] = (lane < t)      ? As[iu[u] * LD + j + 1 + lane]  : 0.0;
                c1v[u] = (lane + 64 < t) ? As[iu[u] * LD + j + 65 + lane] : 0.0;
            }
#pragma unroll
            for (int u = 0; u < 8; ++u) {
                bool ok = (i0 + 4 * u) < n;
                if (ok && lane < t)      As[iu[u] * LD + j + 1 + lane]  = c0v[u] - mult[u] * r0;
                if (ok && lane + 64 < t) As[iu[u] * LD + j + 65 + lane] = c1v[u] - mult[u] * r1;
            }
        }
        __syncthreads();
    }
    if (!dead && tid == n - 1) {             // x = xmax-1: remaining mass
        double pl = As[(n - 1) * LD + (n - 1)];
        myprob = runprod * (1.0 - pl);
    }

    if (tid < Dd) {
        double p = myprob;
        if (!isfinite(p)) p = 0.0;
        if (!(fabs(p) > 1e-15)) p = 0.0;     // reference's flush
        p = fmin(fmax(p, 0.0), 1.0);         // junk-proof projection
        out[k * Dd + tid] = (float)p;
    }
}

// prob_sample = prod_k probs[k, occ[k]]
__global__ void prod_kernel(const int* __restrict__ occ, float* __restrict__ out) {
    if (threadIdx.x == 0) {
        double v = 1.0;
        for (int k = 0; k < Nn; ++k) v *= (double)out[k * Dd + occ[k]];
        if (!isfinite(v)) v = 0.0;
        out[Nn * Dd] = (float)v;
    }
}

extern "C" void kernel_launch(void* const* d_in, const int* in_sizes, int n_in,
                              void* d_out, int out_size, void* d_ws, size_t ws_size,
                              hipStream_t stream) {
    const float* P = (const float*)d_in[0];      // 96x48 f32, row-major
    const int* occ = (const int*)d_in[1];        // 48 int32
    float* out = (float*)d_out;                  // 4609 f32

    slater_kernel<<<Nn, 256, 0, stream>>>(P, occ, out);
    prod_kernel<<<1, 64, 0, stream>>>(occ, out);
}

// Round 19
// 146.166 us; speedup vs baseline: 1.7047x; 1.5872x over previous
//
#include <hip/hip_runtime.h>
#include <math.h>

#define Dd 96
#define Nn 48
#define LD 97
#define PTS 98   // even stride: keeps float2 (8 B) LDS loads aligned

// One block per particle k (P f32; R16-verified math, absmax 7.4e-9).
// R19: rank-4 blocked right-looking LU. Each super-step eliminates cols
// j..j+3: wave 0 preps rows j+1..j+3 (exact partial elimination, FP-identical
// to sequential), then all waves apply the fused 4-term update with the
// multiplier chain computed inline per row. Trailing LDS traffic /4,
// barriers ~/2. Guards/emission identical to R16.
__global__ __launch_bounds__(256, 1) void slater_kernel(const float* __restrict__ P,
                                                        const int* __restrict__ occ,
                                                        float* __restrict__ out) {
    __shared__ double As[Dd * LD];      // 74,496 B
    __shared__ unsigned char flag[Dd];
    float* PT = (float*)As;             // scratch alias; PT reads end before As writes

    const int tid  = threadIdx.x;
    const int k    = blockIdx.x;
    const int n    = Dd - Nn + k + 1;   // xmax
    const int lane = tid & 63;
    const int wave = tid >> 6;
    const int xmin = (k == 0) ? 0 : occ[k - 1] + 1;

    if (tid < Dd) flag[tid] = 0;
    __syncthreads();
    if (tid < k) flag[occ[tid]] = 1;
    for (int e = tid; e < Dd * Nn; e += 256) {       // PT[t][c] = P[c][t]
        int c = e / Nn, t = e - (e / Nn) * Nn;
        PT[t * PTS + c] = P[e];
    }
    __syncthreads();

    // Build A = I*(1-flag) - P P^T in registers via 2x2 tiles, float2 loads.
    double Areg[36];
#pragma unroll
    for (int it = 0; it < 9; ++it) {
        int tau = tid + 256 * it;
        int tr = tau / 48, tc = tau - (tau / 48) * 48;
        int r0 = 2 * tr, c0 = 2 * tc;
        double s00 = 0.0, s01 = 0.0, s10 = 0.0, s11 = 0.0;
        if (r0 < n && c0 < n) {
            for (int t = 0; t < Nn; ++t) {
                const float* row = PT + t * PTS;
                float2 pr = *(const float2*)(row + r0);
                float2 pc = *(const float2*)(row + c0);
                s00 -= (double)pr.x * (double)pc.x; s01 -= (double)pr.x * (double)pc.y;
                s10 -= (double)pr.y * (double)pc.x; s11 -= (double)pr.y * (double)pc.y;
            }
        }
        Areg[it * 4 + 0] = s00; Areg[it * 4 + 1] = s01;
        Areg[it * 4 + 2] = s10; Areg[it * 4 + 3] = s11;
    }
    __syncthreads();                    // all PT reads done before As overwrite
#pragma unroll
    for (int it = 0; it < 9; ++it) {
        int tau = tid + 256 * it;
        int tr = tau / 48, tc = tau - (tau / 48) * 48;
        int r0 = 2 * tr, c0 = 2 * tc;
        if (r0 < n && c0 < n) {
            bool r1ok = (r0 + 1 < n), c1ok = (c0 + 1 < n);
            As[r0 * LD + c0] = Areg[it * 4 + 0] + ((r0 == c0) ? (flag[r0] ? 0.0 : 1.0) : 0.0);
            if (c1ok)
                As[r0 * LD + c0 + 1] = Areg[it * 4 + 1] + ((r0 == c0 + 1) ? (flag[r0] ? 0.0 : 1.0) : 0.0);
            if (r1ok)
                As[(r0 + 1) * LD + c0] = Areg[it * 4 + 2] + ((r0 + 1 == c0) ? (flag[r0 + 1] ? 0.0 : 1.0) : 0.0);
            if (r1ok && c1ok)
                As[(r0 + 1) * LD + c0 + 1] = Areg[it * 4 + 3] + ((r0 + 1 == c0 + 1) ? (flag[r0 + 1] ? 0.0 : 1.0) : 0.0);
        }
    }
    __syncthreads();

    double runprod = 1.0;
    double myprob  = 0.0;
    bool   dead    = false;

    // Guard/emission, identical semantics to R16 (emit BEFORE any cut).
    auto guard = [&](int jj, double pivot) {
        double ap = fabs(pivot);
        if (jj >= xmin) {
            if (tid == jj) myprob = runprod * (1.0 - pivot);
            double newrun = runprod * pivot;
            if (!(ap > 1e-7) || !(ap < 8.0) || !(fabs(newrun) > 1e-8)) dead = true;
            else runprod = newrun;
        } else {
            if (!(ap > 1e-12) || !(ap < 8.0)) dead = true;
        }
    };

    int j = 0;
    // ---- rank-4 super-steps: eliminate cols j..j+3 (all pivots interior) ----
    for (; !dead && j + 4 <= n - 1; j += 4) {
        if (wave == 0) {   // prep rows j+1..j+3 (exact partial elimination)
            double rp0 = 1.0 / As[j * LD + j];
            double m10 = As[(j + 1) * LD + j] * rp0;
            {
                int t = n - (j + 1);
                if (lane < t)      As[(j+1)*LD + j+1+lane]  -= m10 * As[j*LD + j+1+lane];
                if (lane + 64 < t) As[(j+1)*LD + j+65+lane] -= m10 * As[j*LD + j+65+lane];
            }
            double rp1 = 1.0 / As[(j + 1) * LD + (j + 1)];
            double u01 = As[j*LD + j+1], u02 = As[j*LD + j+2];
            double m20 = As[(j + 2) * LD + j] * rp0;
            double m21 = (As[(j + 2) * LD + j + 1] - m20 * u01) * rp1;
            {
                int t = n - (j + 2);
                if (lane < t) {
                    int c = j + 2 + lane;
                    As[(j+2)*LD + c] -= m20 * As[j*LD + c] + m21 * As[(j+1)*LD + c];
                }
                if (lane + 64 < t) {
                    int c = j + 66 + lane;
                    As[(j+2)*LD + c] -= m20 * As[j*LD + c] + m21 * As[(j+1)*LD + c];
                }
            }
            double rp2 = 1.0 / As[(j + 2) * LD + (j + 2)];
            double u12 = As[(j + 1) * LD + j + 2];
            double m30 = As[(j + 3) * LD + j] * rp0;
            double m31 = (As[(j + 3) * LD + j + 1] - m30 * u01) * rp1;
            double m32 = (As[(j + 3) * LD + j + 2] - m30 * u02 - m31 * u12) * rp2;
            {
                int t = n - (j + 3);
                if (lane < t) {
                    int c = j + 3 + lane;
                    As[(j+3)*LD + c] -= m30 * As[j*LD + c] + m31 * As[(j+1)*LD + c] + m32 * As[(j+2)*LD + c];
                }
                if (lane + 64 < t) {
                    int c = j + 67 + lane;
                    As[(j+3)*LD + c] -= m30 * As[j*LD + c] + m31 * As[(j+1)*LD + c] + m32 * As[(j+2)*LD + c];
                }
            }
        }
        __syncthreads();

        double piv0 = As[j * LD + j];
        double piv1 = As[(j + 1) * LD + (j + 1)];
        double piv2 = As[(j + 2) * LD + (j + 2)];
        double piv3 = As[(j + 3) * LD + (j + 3)];
        if (!dead) guard(j + 0, piv0);
        if (!dead) guard(j + 1, piv1);
        if (!dead) guard(j + 2, piv2);
        if (!dead) guard(j + 3, piv3);

        if (!dead) {
            double rp0 = 1.0 / piv0, rp1 = 1.0 / piv1, rp2 = 1.0 / piv2, rp3 = 1.0 / piv3;
            double u01 = As[j*LD + j+1], u02 = As[j*LD + j+2], u03 = As[j*LD + j+3];
            double u12 = As[(j+1)*LD + j+2], u13 = As[(j+1)*LD + j+3];
            double u23 = As[(j+2)*LD + j+3];
            int t = n - (j + 4);
            int c0 = j + 4 + lane, c1 = j + 68 + lane;
            bool ok0 = (lane < t), ok1 = (lane + 64 < t);
            double U0c0 = ok0 ? As[j*LD + c0]     : 0.0;
            double U1c0 = ok0 ? As[(j+1)*LD + c0] : 0.0;
            double U2c0 = ok0 ? As[(j+2)*LD + c0] : 0.0;
            double U3c0 = ok0 ? As[(j+3)*LD + c0] : 0.0;
            double U0c1 = ok1 ? As[j*LD + c1]     : 0.0;
            double U1c1 = ok1 ? As[(j+1)*LD + c1] : 0.0;
            double U2c1 = ok1 ? As[(j+2)*LD + c1] : 0.0;
            double U3c1 = ok1 ? As[(j+3)*LD + c1] : 0.0;
            for (int i = j + 4 + wave; i < n; i += 4) {
                double a0 = As[i*LD + j],     a1 = As[i*LD + j + 1];
                double a2 = As[i*LD + j + 2], a3 = As[i*LD + j + 3];
                double m0 = a0 * rp0;
                double m1 = (a1 - m0 * u01) * rp1;
                double m2 = (a2 - m0 * u02 - m1 * u12) * rp2;
                double m3 = (a3 - m0 * u03 - m1 * u13 - m2 * u23) * rp3;
                if (ok0) As[i*LD + c0] -= m0 * U0c0 + m1 * U1c0 + m2 * U2c0 + m3 * U3c0;
                if (ok1) As[i*LD + c1] -= m0 * U0c1 + m1 * U1c1 + m2 * U2c1 + m3 * U3c1;
            }
        }
        __syncthreads();
    }

    // ---- remainder single steps (R16-proven body) ----
    for (; !dead && j < n - 1; ++j) {
        double pivot = As[j * LD + j];
        guard(j, pivot);
        if (dead) break;
        double rp = 1.0 / pivot;
        int t = n - 1 - j;
        double r0 = (lane < t)      ? As[j*LD + j+1+lane]  : 0.0;
        double r1 = (lane + 64 < t) ? As[j*LD + j+65+lane] : 0.0;
        for (int i = j + 1 + wave; i < n; i += 4) {
            double mult = As[i * LD + j] * rp;
            if (lane < t)      As[i*LD + j+1+lane]  -= mult * r0;
            if (lane + 64 < t) As[i*LD + j+65+lane] -= mult * r1;
        }
        __syncthreads();
    }
    if (!dead && tid == n - 1) {        // x = xmax-1: remaining mass
        double pl = As[(n - 1) * LD + (n - 1)];
        myprob = runprod * (1.0 - pl);
    }

    if (tid < Dd) {
        double p = myprob;
        if (!isfinite(p)) p = 0.0;
        if (!(fabs(p) > 1e-15)) p = 0.0;   // reference's flush
        p = fmin(fmax(p, 0.0), 1.0);       // junk-proof projection
        out[k * Dd + tid] = (float)p;
    }
}

// prob_sample = prod_k probs[k, occ[k]]
__global__ void prod_kernel(const int* __restrict__ occ, float* __restrict__ out) {
    if (threadIdx.x == 0) {
        double v = 1.0;
        for (int k = 0; k < Nn; ++k) v *= (double)out[k * Dd + occ[k]];
        if (!isfinite(v)) v = 0.0;
        out[Nn * Dd] = (float)v;
    }
}

extern "C" void kernel_launch(void* const* d_in, const int* in_sizes, int n_in,
                              void* d_out, int out_size, void* d_ws, size_t ws_size,
                              hipStream_t stream) {
    const float* P = (const float*)d_in[0];      // 96x48 f32, row-major
    const int* occ = (const int*)d_in[1];        // 48 int32
    float* out = (float*)d_out;                  // 4609 f32

    slater_kernel<<<Nn, 256, 0, stream>>>(P, occ, out);
    prod_kernel<<<1, 64, 0, stream>>>(occ, out);
}